// Round 4
// baseline (246.399 us; speedup 1.0000x reference)
//
#include <hip/hip_runtime.h>
#include <math.h>

#define KK 256
#define NN 65536
#define TT 256   // time-tile columns per block (1KB burst per row-visit)
#define WW 16    // scan lookback; decay<=e^-1 -> tail rel err ~e^-16=1e-7 << bf16 eps
#define TPAD 264 // 256 + 8 bf16 pad: row stride 528B = 132 banks (=4 mod 32), 16B-aligned

typedef __bf16 bf16x8 __attribute__((ext_vector_type(8)));
typedef float f32x4 __attribute__((ext_vector_type(4)));

// ---------------------------------------------------------------------------
// Kernel 1: fused row-mean + mu0 + Alpha->bf16 + streaming lams0 fill (NT).
// ---------------------------------------------------------------------------
__global__ __launch_bounds__(512) void prep_kernel(const float* __restrict__ obs,
                                                   const float* __restrict__ Alpha,
                                                   float* __restrict__ mu0,
                                                   __bf16* __restrict__ AlphaB,
                                                   float* __restrict__ out) {
  const int j = blockIdx.x;
  const int tid = threadIdx.x;
  if (tid < KK) AlphaB[(size_t)j * KK + tid] = (__bf16)Alpha[(size_t)j * KK + tid];
  const float4* p = (const float4*)(obs + (size_t)j * NN) + tid;
  float s = 0.f;
#pragma unroll
  for (int i = 0; i < 32; ++i) {
    float4 v = p[i * 512];
    s += (v.x + v.y) + (v.z + v.w);
  }
  __shared__ float red[512];
  red[tid] = s;
  __syncthreads();
  for (int off = 256; off > 0; off >>= 1) {
    if (tid < off) red[tid] += red[tid + off];
    __syncthreads();
  }
  const float m = red[0] * (1.0f / NN) * 0.1f + 0.01f;
  if (tid == 0) mu0[j] = m;

  // lams0 row fill: base out+1 is 4B-misaligned; peel t=0..2 and t=NN-1,
  // stream the rest as aligned nontemporal float4 (never re-read on device).
  float* row0 = out + 1 + (size_t)j * NN;
  if (tid < 3) row0[tid] = m;
  if (tid == 3) row0[NN - 1] = m;
  f32x4* p4 = (f32x4*)(row0 + 3);  // 16B-aligned
  const f32x4 mv = {m, m, m, m};
  for (int i = tid; i < (NN - 4) / 4; i += 512) __builtin_nontemporal_store(mv, p4 + i);
}

// ---------------------------------------------------------------------------
// Kernel 2: fused windowed-scan + bf16-MFMA GEMM + softplus + lams1 + loglik.
//   TT=256: 132KB LDS, 1 block/CU, 8 waves. Scan threads (k, half) each
//   produce 128 cols (WW lookback self-starts any chunk). GEMM wave
//   (wj=w&3, wc=w>>2): j in [64wj,+64) x t in [t0+128wc,+128), acc[4][8].
//   XCD swizzle: 32 blocks/XCD cover a contiguous 8192-col span.
//   lams1 stores are nontemporal: keep L2 for obs tiles (epilogue re-read).
// ---------------------------------------------------------------------------
__global__ __launch_bounds__(512, 2) void main_kernel(const float* __restrict__ obs,
                                                      const float* __restrict__ Beta,
                                                      const float* __restrict__ mu0,
                                                      const __bf16* __restrict__ AlphaB,
                                                      float* __restrict__ out,
                                                      float* __restrict__ bpart) {
  __shared__ __bf16 Slds[TT][TPAD];  // 132 KB
  const int tid = threadIdx.x;
  const int bid = blockIdx.x;
  const int tb = ((bid & 7) << 5) | (bid >> 3);  // bijective: 256 blocks, 32/XCD
  const int t0 = tb * TT;

  // ---- scan: thread (k = tid&255, c = tid>>8) -> S[k, t0+128c .. +127] ----
  {
    const int k = tid & 255;
    const int c = tid >> 8;
    const int tbase = t0 + (c << 7);
    const float beta = Beta[k];
    const float decay = expf(-beta);
    const float* row = obs + (size_t)k * NN;
    float g = 0.f;  // ~ H[k, tbase]; tail rel err < e^-16
    if (tbase > 0) {
      const float4* p = (const float4*)(row + tbase - WW);
#pragma unroll
      for (int i = 0; i < WW / 4; ++i) {
        float4 v = p[i];
        g = decay * (g + v.x);
        g = decay * (g + v.y);
        g = decay * (g + v.z);
        g = decay * (g + v.w);
      }
    }
    const int r0 = c << 7;
    Slds[r0][k] = (__bf16)(beta * g);
    const float4* q = (const float4*)(row + tbase);
#pragma unroll
    for (int i = 0; i < 31; ++i) {
      float4 v = q[i];
      g = decay * (g + v.x); Slds[r0 + 4 * i + 1][k] = (__bf16)(beta * g);
      g = decay * (g + v.y); Slds[r0 + 4 * i + 2][k] = (__bf16)(beta * g);
      g = decay * (g + v.z); Slds[r0 + 4 * i + 3][k] = (__bf16)(beta * g);
      g = decay * (g + v.w); Slds[r0 + 4 * i + 4][k] = (__bf16)(beta * g);
    }
    {  // tail: obs tbase+124..126 -> S rows r0+125..127
      float4 v = q[31];
      g = decay * (g + v.x); Slds[r0 + 125][k] = (__bf16)(beta * g);
      g = decay * (g + v.y); Slds[r0 + 126][k] = (__bf16)(beta * g);
      g = decay * (g + v.z); Slds[r0 + 127][k] = (__bf16)(beta * g);
    }
  }
  __syncthreads();

  // ---- MFMA GEMM ----
  const int wave = tid >> 6;
  const int wj = wave & 3, wc = wave >> 2;
  const int lane = tid & 63;
  const int lquad = lane >> 4;  // k-octet within K=32 step / j-sub in C
  const int l16 = lane & 15;

  f32x4 acc[4][8];  // [jsub][tsub]
#pragma unroll
  for (int a = 0; a < 4; ++a)
#pragma unroll
    for (int b = 0; b < 8; ++b) acc[a][b] = (f32x4){0.f, 0.f, 0.f, 0.f};

  const __bf16* Abase = AlphaB + (size_t)(wj * 64 + l16) * KK + lquad * 8;
  for (int k0 = 0; k0 < KK; k0 += 32) {
    bf16x8 afrag[4];
#pragma unroll
    for (int js = 0; js < 4; ++js)
      afrag[js] = *(const bf16x8*)(Abase + (size_t)js * 16 * KK + k0);
#pragma unroll
    for (int th = 0; th < 2; ++th) {  // 4 bfrag live at a time (VGPR pressure)
      bf16x8 bfrag[4];
#pragma unroll
      for (int q4 = 0; q4 < 4; ++q4)
        bfrag[q4] = *(const bf16x8*)&Slds[wc * 128 + (th * 4 + q4) * 16 + l16]
                                        [k0 + lquad * 8];
#pragma unroll
      for (int js = 0; js < 4; ++js)
#pragma unroll
        for (int q4 = 0; q4 < 4; ++q4)
          acc[js][th * 4 + q4] = __builtin_amdgcn_mfma_f32_16x16x32_bf16(
              afrag[js], bfrag[q4], acc[js][th * 4 + q4], 0, 0, 0);
    }
  }

  // ---- epilogue: softplus, NT lams1 stores (64B lines), loglik partial ----
  float partial = 0.f;
  float* lams1 = out + 1 + (size_t)KK * NN;
  const int tcol = t0 + wc * 128;
#pragma unroll
  for (int js = 0; js < 4; ++js) {
#pragma unroll
    for (int r = 0; r < 4; ++r) {
      const int j = wj * 64 + js * 16 + lquad * 4 + r;  // D row mapping
      const float m = mu0[j];
      const size_t rowoff = (size_t)j * NN + tcol + l16;
#pragma unroll
      for (int ts = 0; ts < 8; ++ts) {
        float v = acc[js][ts][r];                    // v >= 0 always
        float lam = v + __logf(1.f + __expf(-v));    // stable softplus
        if (tcol + ts * 16 + l16 == 0) lam = 0.f;    // lams1[:,0] = 0
        __builtin_nontemporal_store(lam, &lams1[rowoff + ts * 16]);
        const float o = obs[rowoff + ts * 16];       // L2-hot (scan just read it)
        partial += o * __logf(m + lam + 1e-5f) - m - lam;
      }
    }
  }

  // wave reduce, then block reduce through LDS (reused), no atomics
#pragma unroll
  for (int off = 32; off > 0; off >>= 1)
    partial += __shfl_down(partial, off, 64);
  __syncthreads();  // all waves done reading Slds
  float* red = (float*)&Slds[0][0];
  if (lane == 0) red[wave] = partial;
  __syncthreads();
  if (tid == 0) {
    float s = 0.f;
#pragma unroll
    for (int w = 0; w < 8; ++w) s += red[w];
    bpart[bid] = s;
  }
}

// ---------------------------------------------------------------------------
// Kernel 3: sum 256 per-block partials -> out[0]. One block.
// ---------------------------------------------------------------------------
__global__ __launch_bounds__(256) void finish_kernel(const float* __restrict__ bpart,
                                                     float* __restrict__ out) {
  const int tid = threadIdx.x;
  float s = bpart[tid];
#pragma unroll
  for (int off = 32; off > 0; off >>= 1)
    s += __shfl_down(s, off, 64);
  __shared__ float red[4];
  if ((tid & 63) == 0) red[tid >> 6] = s;
  __syncthreads();
  if (tid == 0) out[0] = (red[0] + red[1]) + (red[2] + red[3]);
}

// ---------------------------------------------------------------------------
extern "C" void kernel_launch(void* const* d_in, const int* in_sizes, int n_in,
                              void* d_out, int out_size, void* d_ws, size_t ws_size,
                              hipStream_t stream) {
  const float* obs   = (const float*)d_in[0];
  const float* Beta  = (const float*)d_in[1];
  const float* Alpha = (const float*)d_in[2];
  float* out = (float*)d_out;

  float* mu0 = (float*)d_ws;                // 256 floats
  __bf16* AlphaB = (__bf16*)(mu0 + 256);    // 65536 bf16 = 32768 floats
  float* bpart = (float*)(AlphaB + (size_t)KK * KK);  // 256 floats

  hipLaunchKernelGGL(prep_kernel, dim3(KK), dim3(512), 0, stream, obs, Alpha,
                     mu0, AlphaB, out);
  hipLaunchKernelGGL(main_kernel, dim3(NN / TT), dim3(512), 0, stream,
                     obs, Beta, mu0, AlphaB, out, bpart);
  hipLaunchKernelGGL(finish_kernel, dim3(1), dim3(256), 0, stream, bpart, out);
}

// Round 5
// 232.756 us; speedup vs baseline: 1.0586x; 1.0586x over previous
//
#include <hip/hip_runtime.h>
#include <math.h>

#define KK 256
#define NN 65536
#define TT 128   // time-tile columns per block; 67.6KB LDS -> 2 blocks/CU
#define WW 16    // scan lookback; decay<=e^-1 -> tail rel err ~e^-16=1e-7 << bf16 eps
#define TPAD 264 // 256 + 8 bf16 pad: breaks 512B-stride bank aliasing, keeps 16B align
#define NB (NN / TT)     // 512 blocks
#define NCHUNK (NB * 2)  // 1024 rowsum chunks (2 per block)

typedef __bf16 bf16x8 __attribute__((ext_vector_type(8)));
typedef float f32x4 __attribute__((ext_vector_type(4)));

// ---------------------------------------------------------------------------
// Kernel 1: Alpha -> bf16 convert, zero loglik accumulator (d_out poisoned).
// ---------------------------------------------------------------------------
__global__ __launch_bounds__(256) void alpha_kernel(const float* __restrict__ Alpha,
                                                    __bf16* __restrict__ AlphaB,
                                                    float* __restrict__ out) {
  const int i = blockIdx.x * 256 + threadIdx.x;
  AlphaB[i] = (__bf16)Alpha[i];
  if (i == 0) out[0] = 0.f;
}

// ---------------------------------------------------------------------------
// Kernel 2: fused windowed-scan + rowsum partials + bf16-MFMA GEMM +
//           softplus + lams1 store. NO mu0 dependency, NO obs re-read.
//   512 threads: scan thread (k, c) produces S[k, t0+64c .. +63] and its
//   chunk row-sum (feeds mu0 downstream). 8 waves: wave (wj=w&3, wc=w>>2)
//   computes j in [64wj,+64) x t in [t0+64wc,+64). XCD swizzle keeps each
//   XCD on a contiguous 8192-col span (L2 write locality).
// ---------------------------------------------------------------------------
__global__ __launch_bounds__(512, 4) void main_kernel(const float* __restrict__ obs,
                                                      const float* __restrict__ Beta,
                                                      const __bf16* __restrict__ AlphaB,
                                                      float* __restrict__ out,
                                                      float* __restrict__ P) {
  __shared__ __bf16 Slds[TT][TPAD];  // 67.6 KB
  const int tid = threadIdx.x;
  const int bid = blockIdx.x;
  const int tb = ((bid & 7) << 6) | (bid >> 3);  // bijective: 512 blocks, 64/XCD
  const int t0 = tb * TT;

  // ---- scan + rowsum: thread (k = tid&255, c = tid>>8) ----
  {
    const int k = tid & 255;
    const int c = tid >> 8;
    const int tbase = t0 + (c << 6);
    const float beta = Beta[k];
    const float decay = expf(-beta);
    const float* row = obs + (size_t)k * NN;
    float g = 0.f;  // ~ H[k, tbase]; tail rel err < e^-16
    if (tbase > 0) {
      const float4* p = (const float4*)(row + tbase - WW);
#pragma unroll
      for (int i = 0; i < WW / 4; ++i) {
        float4 v = p[i];
        g = decay * (g + v.x);
        g = decay * (g + v.y);
        g = decay * (g + v.z);
        g = decay * (g + v.w);
      }
    }
    const int r0 = c << 6;
    Slds[r0][k] = (__bf16)(beta * g);
    const float4* q = (const float4*)(row + tbase);
    float s = 0.f;  // chunk row-sum (cols tbase..tbase+63, each exactly once)
#pragma unroll
    for (int i = 0; i < 15; ++i) {
      float4 v = q[i];
      s += (v.x + v.y) + (v.z + v.w);
      g = decay * (g + v.x); Slds[r0 + 4 * i + 1][k] = (__bf16)(beta * g);
      g = decay * (g + v.y); Slds[r0 + 4 * i + 2][k] = (__bf16)(beta * g);
      g = decay * (g + v.z); Slds[r0 + 4 * i + 3][k] = (__bf16)(beta * g);
      g = decay * (g + v.w); Slds[r0 + 4 * i + 4][k] = (__bf16)(beta * g);
    }
    {  // tail: obs tbase+60..62 feed S rows r0+61..63; col 63 only in rowsum
      float4 v = q[15];
      s += (v.x + v.y) + (v.z + v.w);
      g = decay * (g + v.x); Slds[r0 + 61][k] = (__bf16)(beta * g);
      g = decay * (g + v.y); Slds[r0 + 62][k] = (__bf16)(beta * g);
      g = decay * (g + v.z); Slds[r0 + 63][k] = (__bf16)(beta * g);
    }
    P[(size_t)(2 * bid + c) * KK + k] = s;  // coalesced 1KB per half-block
  }
  __syncthreads();

  // ---- MFMA GEMM ----
  const int wave = tid >> 6;
  const int wj = wave & 3, wc = wave >> 2;
  const int lane = tid & 63;
  const int lquad = lane >> 4;  // k-octet within K=32 step / j-sub in C
  const int l16 = lane & 15;

  f32x4 acc[4][4];  // [jsub][tsub]
#pragma unroll
  for (int a = 0; a < 4; ++a)
#pragma unroll
    for (int b = 0; b < 4; ++b) acc[a][b] = (f32x4){0.f, 0.f, 0.f, 0.f};

  const __bf16* Abase = AlphaB + (size_t)(wj * 64 + l16) * KK + lquad * 8;
  for (int k0 = 0; k0 < KK; k0 += 32) {
    bf16x8 afrag[4], bfrag[4];
#pragma unroll
    for (int js = 0; js < 4; ++js)
      afrag[js] = *(const bf16x8*)(Abase + (size_t)js * 16 * KK + k0);
#pragma unroll
    for (int ts = 0; ts < 4; ++ts)
      bfrag[ts] = *(const bf16x8*)&Slds[wc * 64 + ts * 16 + l16][k0 + lquad * 8];
#pragma unroll
    for (int js = 0; js < 4; ++js)
#pragma unroll
      for (int ts = 0; ts < 4; ++ts)
        acc[js][ts] = __builtin_amdgcn_mfma_f32_16x16x32_bf16(
            afrag[js], bfrag[ts], acc[js][ts], 0, 0, 0);
  }

  // ---- epilogue: softplus + lams1 stores (64B lines per 16-lane group) ----
  float* lams1 = out + 1 + (size_t)KK * NN;
  const int tcol = t0 + wc * 64;
#pragma unroll
  for (int js = 0; js < 4; ++js) {
#pragma unroll
    for (int r = 0; r < 4; ++r) {
      const int j = wj * 64 + js * 16 + lquad * 4 + r;  // D row mapping
      const size_t rowoff = (size_t)j * NN + tcol + l16;
#pragma unroll
      for (int ts = 0; ts < 4; ++ts) {
        float v = acc[js][ts][r];                    // v >= 0 always
        float lam = v + __logf(1.f + __expf(-v));    // stable softplus
        if (tcol + ts * 16 + l16 == 0) lam = 0.f;    // lams1[:,0] = 0
        lams1[rowoff + ts * 16] = lam;
      }
    }
  }
}

// ---------------------------------------------------------------------------
// Kernel 3: block j: reduce P[:,j] -> mu0_j; stream obs row j + lams1 row j
//           (coalesced, L3-hot from main), write lams0 row j, loglik partial.
//           One atomic per block (256 total).
// ---------------------------------------------------------------------------
__global__ __launch_bounds__(512) void loglik_kernel(const float* __restrict__ obs,
                                                     const float* __restrict__ P,
                                                     float* __restrict__ out) {
  const int j = blockIdx.x;
  const int tid = threadIdx.x;

  // mu0_j = (sum_t obs[j,t])/NN * 0.1 + 0.01 from chunk partials
  float s = 0.f;
#pragma unroll
  for (int c = 0; c < NCHUNK / 512; ++c)
    s += P[(size_t)(tid + c * 512) * KK + j];
  __shared__ float red[512];
  red[tid] = s;
  __syncthreads();
  for (int off = 256; off > 0; off >>= 1) {
    if (tid < off) red[tid] += red[tid + off];
    __syncthreads();
  }
  const float m = red[0] * (1.0f / NN) * 0.1f + 0.01f;

  const float* orow = obs + (size_t)j * NN;
  float* l0row = out + 1 + (size_t)j * NN;
  float* l1row = l0row + (size_t)KK * NN;
  float partial = 0.f;
#pragma unroll 8
  for (int i = 0; i < NN / 512; ++i) {
    const int t = tid + i * 512;          // coalesced scalar streams
    const float l1 = l1row[t];
    const float o = orow[t];
    l0row[t] = m;
    partial += o * __logf(m + l1 + 1e-5f) - m - l1;
  }

  // wave reduce -> block reduce -> one atomic
#pragma unroll
  for (int off = 32; off > 0; off >>= 1)
    partial += __shfl_down(partial, off, 64);
  __syncthreads();
  if ((tid & 63) == 0) red[tid >> 6] = partial;
  __syncthreads();
  if (tid == 0) {
    float t = 0.f;
#pragma unroll
    for (int w = 0; w < 8; ++w) t += red[w];
    atomicAdd(out, t);
  }
}

// ---------------------------------------------------------------------------
extern "C" void kernel_launch(void* const* d_in, const int* in_sizes, int n_in,
                              void* d_out, int out_size, void* d_ws, size_t ws_size,
                              hipStream_t stream) {
  const float* obs   = (const float*)d_in[0];
  const float* Beta  = (const float*)d_in[1];
  const float* Alpha = (const float*)d_in[2];
  float* out = (float*)d_out;

  __bf16* AlphaB = (__bf16*)d_ws;                     // 128 KB
  float* P = (float*)(AlphaB + (size_t)KK * KK);      // 1024 x 256 floats = 1 MB

  hipLaunchKernelGGL(alpha_kernel, dim3(KK), dim3(256), 0, stream, Alpha, AlphaB, out);
  hipLaunchKernelGGL(main_kernel, dim3(NB), dim3(512), 0, stream,
                     obs, Beta, AlphaB, out, P);
  hipLaunchKernelGGL(loglik_kernel, dim3(KK), dim3(512), 0, stream, obs, P, out);
}

// Round 6
// 228.483 us; speedup vs baseline: 1.0784x; 1.0187x over previous
//
#include <hip/hip_runtime.h>
#include <math.h>

#define KK 256
#define NN 65536
#define TT 128   // time-tile columns per block; 67.6KB LDS -> 2 blocks/CU
#define TPAD 264 // 256 + 8 bf16 pad: breaks 512B-stride bank aliasing, keeps 16B align
#define NB (NN / TT)  // 512 blocks; 1 rowsum chunk per block

typedef __bf16 bf16x8 __attribute__((ext_vector_type(8)));
typedef float f32x4 __attribute__((ext_vector_type(4)));

// ---------------------------------------------------------------------------
// Kernel 1: Alpha -> bf16 convert, zero loglik accumulator (d_out poisoned).
// ---------------------------------------------------------------------------
__global__ __launch_bounds__(256) void alpha_kernel(const float* __restrict__ Alpha,
                                                    __bf16* __restrict__ AlphaB,
                                                    float* __restrict__ out) {
  const int i = blockIdx.x * 256 + threadIdx.x;
  AlphaB[i] = (__bf16)Alpha[i];
  if (i == 0) out[0] = 0.f;
}

// ---------------------------------------------------------------------------
// Kernel 2: fused wave-cooperative scan + rowsum + bf16-MFMA GEMM + softplus
//           + lams1 store.
//   Scan: octet-per-row. 8 lanes share row k; lane l owns t = 8*rnd + l.
//   Loads are 32B-contiguous per octet (8 line-streams/wave vs 64 before ->
//   MSHR-friendly). Recurrence H[t]=d*(H[t-1]+o[t-1]) crosses lanes: per
//   8-col round, Hillis-Steele weighted inclusive scan I_l = sum d^(l-m) u_m
//   (3 masked shfl_up), then H[base+l] = d^l*Hc + d*I_{l-1}; carry
//   Hc' = d^8*Hc + d*I_7. Algebraically identical to the serial scan.
//   Window: 2 rounds over [t0-16, t0) (tail rel err ~e^-16, as before).
//   LDS S-writes at t=8i+l: banks (4l + (k>>1)) mod 32 -> 2 lanes/bank, free.
// ---------------------------------------------------------------------------
__global__ __launch_bounds__(512, 4) void main_kernel(const float* __restrict__ obs,
                                                      const float* __restrict__ Beta,
                                                      const __bf16* __restrict__ AlphaB,
                                                      float* __restrict__ out,
                                                      float* __restrict__ P) {
  __shared__ __bf16 Slds[TT][TPAD];  // 67.6 KB
  const int tid = threadIdx.x;
  const int bid = blockIdx.x;
  const int tb = ((bid & 7) << 6) | (bid >> 3);  // bijective XCD swizzle (512 blocks)
  const int t0 = tb * TT;

  // ---- scan phase: 64 rows in flight (8 lanes each), 4 row-iterations ----
  {
    const int ell = tid & 7;
    const int krow0 = tid >> 3;  // 0..63
    for (int it = 0; it < 4; ++it) {
      const int k = it * 64 + krow0;
      const float beta = Beta[k];
      const float d = expf(-beta);
      const float d2 = d * d, d4 = d2 * d2, d8 = d4 * d4;
      float dl = 1.f;  // d^ell
      if (ell & 1) dl *= d;
      if (ell & 2) dl *= d2;
      if (ell & 4) dl *= d4;
      const float* row = obs + (size_t)k * NN;
      float Hc = 0.f;  // carry ~ H[base]; window gives tail rel err < e^-16
      if (t0 > 0) {
#pragma unroll
        for (int rnd = 0; rnd < 2; ++rnd) {
          const float u = row[t0 - 16 + rnd * 8 + ell];
          float X = u, y;
          y = __shfl_up(X, 1, 8); X += (ell >= 1 ? d  * y : 0.f);
          y = __shfl_up(X, 2, 8); X += (ell >= 2 ? d2 * y : 0.f);
          y = __shfl_up(X, 4, 8); X += (ell >= 4 ? d4 * y : 0.f);
          const float I7 = __shfl(X, 7, 8);
          Hc = d8 * Hc + d * I7;
        }
      }
      float rsum = 0.f;
#pragma unroll
      for (int rnd = 0; rnd < 16; ++rnd) {
        const int base = 8 * rnd;  // relative to t0
        const float u = row[t0 + base + ell];
        rsum += u;
        float X = u, y;
        y = __shfl_up(X, 1, 8); X += (ell >= 1 ? d  * y : 0.f);
        y = __shfl_up(X, 2, 8); X += (ell >= 2 ? d2 * y : 0.f);
        y = __shfl_up(X, 4, 8); X += (ell >= 4 ? d4 * y : 0.f);
        const float Ip = __shfl_up(X, 1, 8);           // I_{ell-1}
        const float H = dl * Hc + (ell >= 1 ? d * Ip : 0.f);
        Slds[base + ell][k] = (__bf16)(beta * H);
        const float I7 = __shfl(X, 7, 8);
        Hc = d8 * Hc + d * I7;                         // after H uses old Hc
      }
      // octet rowsum reduce -> one P entry per row per block
      rsum += __shfl_down(rsum, 1, 8);
      rsum += __shfl_down(rsum, 2, 8);
      rsum += __shfl_down(rsum, 4, 8);
      if (ell == 0) P[(size_t)tb * KK + k] = rsum;
    }
  }
  __syncthreads();

  // ---- MFMA GEMM: wave (wj=w&3, wc=w>>2): j in [64wj,+64) x t in [64wc,+64) ----
  const int wave = tid >> 6;
  const int wj = wave & 3, wc = wave >> 2;
  const int lane = tid & 63;
  const int lquad = lane >> 4;  // k-octet within K=32 step / j-sub in C
  const int l16 = lane & 15;

  f32x4 acc[4][4];  // [jsub][tsub]
#pragma unroll
  for (int a = 0; a < 4; ++a)
#pragma unroll
    for (int b = 0; b < 4; ++b) acc[a][b] = (f32x4){0.f, 0.f, 0.f, 0.f};

  const __bf16* Abase = AlphaB + (size_t)(wj * 64 + l16) * KK + lquad * 8;
  for (int k0 = 0; k0 < KK; k0 += 32) {
    bf16x8 afrag[4], bfrag[4];
#pragma unroll
    for (int js = 0; js < 4; ++js)
      afrag[js] = *(const bf16x8*)(Abase + (size_t)js * 16 * KK + k0);
#pragma unroll
    for (int ts = 0; ts < 4; ++ts)
      bfrag[ts] = *(const bf16x8*)&Slds[wc * 64 + ts * 16 + l16][k0 + lquad * 8];
#pragma unroll
    for (int js = 0; js < 4; ++js)
#pragma unroll
      for (int ts = 0; ts < 4; ++ts)
        acc[js][ts] = __builtin_amdgcn_mfma_f32_16x16x32_bf16(
            afrag[js], bfrag[ts], acc[js][ts], 0, 0, 0);
  }

  // ---- epilogue: softplus + lams1 stores (64B lines per 16-lane group) ----
  float* lams1 = out + 1 + (size_t)KK * NN;
  const int tcol = t0 + wc * 64;
#pragma unroll
  for (int js = 0; js < 4; ++js) {
#pragma unroll
    for (int r = 0; r < 4; ++r) {
      const int j = wj * 64 + js * 16 + lquad * 4 + r;  // D row mapping
      const size_t rowoff = (size_t)j * NN + tcol + l16;
#pragma unroll
      for (int ts = 0; ts < 4; ++ts) {
        float v = acc[js][ts][r];                    // v >= 0 always
        float lam = v + __logf(1.f + __expf(-v));    // stable softplus
        if (tcol + ts * 16 + l16 == 0) lam = 0.f;    // lams1[:,0] = 0
        lams1[rowoff + ts * 16] = lam;
      }
    }
  }
}

// ---------------------------------------------------------------------------
// Kernel 3: block j: reduce P[:,j] -> mu0_j; stream obs row j + lams1 row j
//           (coalesced, L3-hot from main), write lams0 row j, loglik partial.
//           One atomic per block (256 total).
// ---------------------------------------------------------------------------
__global__ __launch_bounds__(512) void loglik_kernel(const float* __restrict__ obs,
                                                     const float* __restrict__ P,
                                                     float* __restrict__ out) {
  const int j = blockIdx.x;
  const int tid = threadIdx.x;

  // mu0_j from the 512 per-block chunk partials
  float s = P[(size_t)tid * KK + j];
  __shared__ float red[512];
  red[tid] = s;
  __syncthreads();
  for (int off = 256; off > 0; off >>= 1) {
    if (tid < off) red[tid] += red[tid + off];
    __syncthreads();
  }
  const float m = red[0] * (1.0f / NN) * 0.1f + 0.01f;

  const float* orow = obs + (size_t)j * NN;
  float* l0row = out + 1 + (size_t)j * NN;
  float* l1row = l0row + (size_t)KK * NN;
  float partial = 0.f;
#pragma unroll 8
  for (int i = 0; i < NN / 512; ++i) {
    const int t = tid + i * 512;          // coalesced scalar streams
    const float l1 = l1row[t];
    const float o = orow[t];
    l0row[t] = m;
    partial += o * __logf(m + l1 + 1e-5f) - m - l1;
  }

  // wave reduce -> block reduce -> one atomic
#pragma unroll
  for (int off = 32; off > 0; off >>= 1)
    partial += __shfl_down(partial, off, 64);
  __syncthreads();
  if ((tid & 63) == 0) red[tid >> 6] = partial;
  __syncthreads();
  if (tid == 0) {
    float t = 0.f;
#pragma unroll
    for (int w = 0; w < 8; ++w) t += red[w];
    atomicAdd(out, t);
  }
}

// ---------------------------------------------------------------------------
extern "C" void kernel_launch(void* const* d_in, const int* in_sizes, int n_in,
                              void* d_out, int out_size, void* d_ws, size_t ws_size,
                              hipStream_t stream) {
  const float* obs   = (const float*)d_in[0];
  const float* Beta  = (const float*)d_in[1];
  const float* Alpha = (const float*)d_in[2];
  float* out = (float*)d_out;

  __bf16* AlphaB = (__bf16*)d_ws;                     // 128 KB
  float* P = (float*)(AlphaB + (size_t)KK * KK);      // 512 x 256 floats = 512 KB

  hipLaunchKernelGGL(alpha_kernel, dim3(KK), dim3(256), 0, stream, Alpha, AlphaB, out);
  hipLaunchKernelGGL(main_kernel, dim3(NB), dim3(512), 0, stream,
                     obs, Beta, AlphaB, out, P);
  hipLaunchKernelGGL(loglik_kernel, dim3(KK), dim3(512), 0, stream, obs, P, out);
}